// Round 4
// baseline (1431.253 us; speedup 1.0000x reference)
//
#include <hip/hip_runtime.h>
#include <cstdint>
#include <cstddef>

#define HID 128

// ---------- helpers ----------
__device__ __forceinline__ float bf2f(uint32_t u) {
    union { uint32_t i; float f; } x; x.i = u << 16; return x.f;
}
__device__ __forceinline__ float bflo(uint32_t p) { return bf2f(p & 0xffffu); }
__device__ __forceinline__ float bfhi(uint32_t p) { return bf2f(p >> 16); }
__device__ __forceinline__ float bfs(const uint16_t* p) { return bf2f((uint32_t)*p); }
__device__ __forceinline__ uint16_t f2bf(float f) {
    union { float f; uint32_t i; } x; x.f = f;
    uint32_t u = x.i;
    return (uint16_t)((u + 0x7fffu + ((u >> 16) & 1u)) >> 16);   // RNE
}
__device__ __forceinline__ uint32_t pack2(float a, float b) {
    return (uint32_t)f2bf(a) | ((uint32_t)f2bf(b) << 16);
}
__device__ __forceinline__ float lrelu_f(float v) { return v > 0.f ? v : 0.01f * v; }

// ---------- ws-too-small sentinel: out = 65536.0 everywhere (fp32) ----------
__global__ __launch_bounds__(256) void sentinel_kernel(float* out, int n) {
    int i = blockIdx.x * 256 + threadIdx.x;
    if (i < n) out[i] = 65536.0f;
}

// ---------- dtype probes ----------
// edge_index: int64 layout has all odd 32-bit words == 0 (values < 2^31)
__global__ void detect_e_kernel(const int* __restrict__ ei, int* __restrict__ flagE) {
    int lane = threadIdx.x;                       // 64 threads
    int w = ei[2 * lane + 1];
    unsigned long long b = __ballot(w != 0);
    if (lane == 0) flagE[0] = (b == 0ULL) ? 1 : 0;   // 1 = int64
}
// x: if fp32, bits14:7 of each word are mid-mantissa bits -> effectively uniform.
// if bf16 pairs, bits14:7 are the low bf16's exponent of N(0,1) data: in [64,144].
__global__ void detect_f_kernel(const uint32_t* __restrict__ x, int* __restrict__ flagF) {
    int lane = threadIdx.x;                       // 64 threads
    uint32_t e = (x[lane] >> 7) & 0xFFu;
    unsigned long long b = __ballot(e >= 64u && e <= 144u);
    if (lane == 0) flagF[0] = (b == ~0ULL) ? 0 : 1;  // 1 = fp32, 0 = bf16
}

// ---------- weight pre-transpose: W[n][k] -> Wt[k][n] bf16 ----------
struct TransArgs {
    const void* src[8];
    uint16_t* dst[8];
    int nrows[8];
};
__global__ __launch_bounds__(256) void transpose_w(TransArgs a, const int* __restrict__ flagF) {
    int mat = blockIdx.x >> 6;                    // 64 blocks per matrix
    int idx = ((blockIdx.x & 63) << 8) + threadIdx.x;
    int n = a.nrows[mat];
    if (idx < n * HID) {
        uint16_t v = flagF[0] ? f2bf(((const float*)a.src[mat])[idx])
                              : ((const uint16_t*)a.src[mat])[idx];
        int r = idx >> 7, k = idx & 127;
        a.dst[mat][k * n + r] = v;
    }
}

// ---------- param vectors -> canonical fp32 buffer ----------
struct ParamArgs {
    const void* src[14];
    int off[14];
    int cnt[14];
};
__global__ __launch_bounds__(128) void convert_params(ParamArgs pa, float* __restrict__ params,
                                                      const int* __restrict__ flagF) {
    int b = blockIdx.x, t = threadIdx.x;          // 14 blocks x 128
    if (t < pa.cnt[b]) {
        float v = flagF[0] ? ((const float*)pa.src[b])[t]
                           : bfs(&((const uint16_t*)pa.src[b])[t]);
        params[pa.off[b] + t] = v;
    }
}

// ---------- x -> canonical bf16 feature buffer ----------
__global__ __launch_bounds__(256) void convert_x(const void* __restrict__ x,
                                                 uint32_t* __restrict__ dst,
                                                 const int* __restrict__ flagF, int total2) {
    int i = blockIdx.x * 256 + threadIdx.x;
    if (i >= total2) return;
    if (flagF[0]) {
        float2 v = ((const float2*)x)[i];
        dst[i] = pack2(v.x, v.y);
    } else {
        dst[i] = ((const uint32_t*)x)[i];
    }
}

// ---------- CSR build ----------
__global__ __launch_bounds__(256) void hist_kernel(const int* __restrict__ ei,
                                                   const int* __restrict__ flagE,
                                                   int* deg, int E) {
    int e = blockIdx.x * 256 + threadIdx.x;
    if (e < E) {
        int d = flagE[0] ? ei[2 * (E + e)] : ei[E + e];
        atomicAdd(&deg[d], 1);
    }
}
__global__ __launch_bounds__(256) void scan_a(const int* deg, int* scanbuf, int M, int CH) {
    int i = blockIdx.x * 256 + threadIdx.x;       // 0..1023
    int s = i * CH, e = min(s + CH, M);
    int t = 0;
    for (int j = s; j < e; ++j) t += deg[j];
    scanbuf[i] = t;
}
__global__ __launch_bounds__(1024) void scan_b(int* scanbuf) {
    __shared__ int sm[1024];
    int tid = threadIdx.x;
    int v = scanbuf[tid];
    sm[tid] = v;
    __syncthreads();
    for (int off = 1; off < 1024; off <<= 1) {
        int t = (tid >= off) ? sm[tid - off] : 0;
        __syncthreads();
        sm[tid] += t;
        __syncthreads();
    }
    scanbuf[tid] = sm[tid] - v;                   // exclusive prefix
}
__global__ __launch_bounds__(256) void scan_c(int* deg_then_cursor, const int* scanbuf,
                                              int* rowptr, int M, int E, int CH) {
    int i = blockIdx.x * 256 + threadIdx.x;       // 0..1023
    int run = scanbuf[i];
    int s = i * CH, e = min(s + CH, M);
    for (int j = s; j < e; ++j) {
        int d = deg_then_cursor[j];
        rowptr[j] = run;
        deg_then_cursor[j] = run;                 // becomes fill cursor
        run += d;
    }
    if (i == 0) rowptr[M] = E;
}
__global__ __launch_bounds__(256) void fill_kernel(const int* __restrict__ ei,
                                                   const int* __restrict__ flagE,
                                                   int* cursor, int* csr, int E) {
    int e = blockIdx.x * 256 + threadIdx.x;
    if (e < E) {
        int isl = flagE[0];
        int s = isl ? ei[2 * e] : ei[e];
        int d = isl ? ei[2 * (E + e)] : ei[E + e];
        int p = atomicAdd(&cursor[d], 1);
        csr[p] = s;
    }
}

// ---------- per-node max aggregation over bf16 rows (no atomics) ----------
__global__ __launch_bounds__(256) void gather_kernel(const uint32_t* __restrict__ cur,
                                                     const int* __restrict__ rowptr,
                                                     const int* __restrict__ csr,
                                                     uint32_t* __restrict__ agg, int M) {
    int wid = (int)((blockIdx.x * 256 + threadIdx.x) >> 6);   // one node per wave
    int lane = threadIdx.x & 63;
    if (wid >= M) return;
    int b = rowptr[wid], e = rowptr[wid + 1];
    float mx = -INFINITY, my = -INFINITY;
    for (int i = b; i < e; ++i) {
        int s = csr[i];
        uint32_t u = cur[(size_t)s * 64 + lane];
        mx = fmaxf(mx, bflo(u));
        my = fmaxf(my, bfhi(u));
    }
    if (b == e) { mx = 0.f; my = 0.f; }           // no neighbors -> 0 (isfinite rule)
    agg[(size_t)wid * 64 + lane] = pack2(mx, my); // exact repack of bf16 values
}

// ---------- GEMM: out[M][N] = sum_s A_s @ Wt_s + bias ----------
// A_s: bf16 [M][128]; Wt_s: bf16 [128][N] (pre-transposed); bias fp32.
// In-place (out aliases A0) is safe: blocks only read/write their own 128 rows,
// and all global A reads complete before the barrier preceding epilogue stores.
template<int N, int NSRC, bool ACT, bool OUTF32>
__global__ __launch_bounds__(256) void gemm_kernel(
    const uint16_t* __restrict__ A0, const uint16_t* __restrict__ Wt0,
    const uint16_t* __restrict__ A1, const uint16_t* __restrict__ Wt1,
    const float* __restrict__ bias, void* __restrict__ out_, int M)
{
    constexpr int CPT = N / 32;                   // cols per thread (4 or 2)
    __shared__ float As[32 * 128];                // [k][row], Mtile=128, KT=32
    __shared__ uint16_t Ws[32 * N];               // [k][n] bf16
    const int tid = threadIdx.x;
    const int c = tid & 31;                       // col-thread
    const int rg = tid >> 5;                      // row group (16 rows each)
    const int row0 = blockIdx.x * 128;
    const int ar = tid >> 1, ah = tid & 1;        // staging: row, k-half
    const int gm = row0 + ar;

    float acc[16][CPT];
#pragma unroll
    for (int r = 0; r < 16; ++r)
#pragma unroll
        for (int j = 0; j < CPT; ++j) acc[r][j] = 0.f;

#pragma unroll 1
    for (int s = 0; s < NSRC; ++s) {
        const uint16_t* Ag = (s == 0) ? A0 : A1;
        const uint16_t* Wg = (s == 0) ? Wt0 : Wt1;
#pragma unroll 1
        for (int kc = 0; kc < 4; ++kc) {
            __syncthreads();
            // stage A tile transposed into LDS as fp32 [k][row]
            uint4 p0 = make_uint4(0, 0, 0, 0), p1 = p0;
            if (gm < M) {
                const uint4* ap = (const uint4*)(Ag + (size_t)gm * HID + kc * 32 + ah * 16);
                p0 = ap[0]; p1 = ap[1];
            }
            uint32_t u[8] = {p0.x, p0.y, p0.z, p0.w, p1.x, p1.y, p1.z, p1.w};
#pragma unroll
            for (int i = 0; i < 8; ++i) {
                As[(ah * 16 + 2 * i) * 128 + ar] = bflo(u[i]);
                As[(ah * 16 + 2 * i + 1) * 128 + ar] = bfhi(u[i]);
            }
            // stage W tile: straight conflict-free copy (Wt pre-transposed)
            const uint4* wsrc = (const uint4*)(Wg + kc * 32 * N);
            ((uint4*)Ws)[tid] = wsrc[tid];
            if constexpr (N == 128) ((uint4*)Ws)[tid + 256] = wsrc[tid + 256];
            __syncthreads();
#pragma unroll 8
            for (int k = 0; k < 32; ++k) {
                float a[16];
                const float4* asr = (const float4*)&As[k * 128 + rg * 16];
#pragma unroll
                for (int j = 0; j < 4; ++j) ((float4*)a)[j] = asr[j];
                float w[CPT];
                if constexpr (CPT == 4) {
                    uint2 ww = *(const uint2*)&Ws[k * N + (c << 2)];
                    w[0] = bflo(ww.x); w[1] = bfhi(ww.x);
                    w[2] = bflo(ww.y); w[3] = bfhi(ww.y);
                } else {
                    uint32_t ww = *(const uint32_t*)&Ws[k * N + (c << 1)];
                    w[0] = bflo(ww); w[1] = bfhi(ww);
                }
#pragma unroll
                for (int r = 0; r < 16; ++r)
#pragma unroll
                    for (int j = 0; j < CPT; ++j)
                        acc[r][j] = fmaf(a[r], w[j], acc[r][j]);
            }
        }
    }
    float bj[CPT];
#pragma unroll
    for (int j = 0; j < CPT; ++j) bj[j] = bias[c * CPT + j];
#pragma unroll
    for (int r = 0; r < 16; ++r) {
        int m = row0 + rg * 16 + r;
        if (m < M) {
            float o[CPT];
#pragma unroll
            for (int j = 0; j < CPT; ++j) {
                o[j] = acc[r][j] + bj[j];
                if constexpr (ACT) o[j] = lrelu_f(o[j]);
            }
            if constexpr (OUTF32) {
                *(float2*)&((float*)out_)[(size_t)m * N + (c << 1)] = make_float2(o[0], o[1]);
            } else {
                ushort4 ov;
                ov.x = f2bf(o[0]); ov.y = f2bf(o[1]); ov.z = f2bf(o[2]); ov.w = f2bf(o[3]);
                *(ushort4*)&((uint16_t*)out_)[(size_t)m * N + (c << 2)] = ov;
            }
        }
    }
}

// ---------- batch norm over bf16 z ----------
__global__ __launch_bounds__(256) void bn_stats(const uint32_t* __restrict__ z,
                                                float* __restrict__ stats, int M, int rpb) {
    __shared__ float4 red[256];
    int c2 = threadIdx.x & 63;                    // uint32 column (2 features)
    int part = threadIdx.x >> 6;                  // 0..3
    int s0 = blockIdx.x * rpb, e0 = min(s0 + rpb, M);
    float sl = 0.f, s2l = 0.f, sh = 0.f, s2h = 0.f;
    for (int r = s0 + part; r < e0; r += 4) {
        uint32_t u = z[(size_t)r * 64 + c2];
        float a = bflo(u), b = bfhi(u);
        sl += a; s2l = fmaf(a, a, s2l);
        sh += b; s2h = fmaf(b, b, s2h);
    }
    red[threadIdx.x] = make_float4(sl, s2l, sh, s2h);
    __syncthreads();
    if (threadIdx.x < 64) {
        float4 v = red[threadIdx.x];
        float4 v1 = red[threadIdx.x + 64], v2 = red[threadIdx.x + 128], v3 = red[threadIdx.x + 192];
        v.x += v1.x + v2.x + v3.x; v.y += v1.y + v2.y + v3.y;
        v.z += v1.z + v2.z + v3.z; v.w += v1.w + v2.w + v3.w;
        int cc = c2 * 2;
        atomicAdd(&stats[cc], v.x);
        atomicAdd(&stats[128 + cc], v.y);
        atomicAdd(&stats[cc + 1], v.z);
        atomicAdd(&stats[129 + cc], v.w);
    }
}
__global__ void bn_finalize(float* stats, const float* __restrict__ g,
                            const float* __restrict__ be, int M) {
    int c = threadIdx.x;                          // 128 threads
    float mean = stats[c] / (float)M;
    float var = stats[128 + c] / (float)M - mean * mean;
    float sc = g[c] * rsqrtf(var + 1e-5f);
    stats[c] = sc;
    stats[128 + c] = be[c] - mean * sc;
}
__global__ __launch_bounds__(256) void bn_apply(uint32_t* __restrict__ z,
                                                const float* __restrict__ stats, int total2) {
    int i = blockIdx.x * 256 + threadIdx.x;
    if (i >= total2) return;
    int cc = (i & 63) * 2;
    uint32_t u = z[i];
    float a = lrelu_f(fmaf(bflo(u), stats[cc], stats[128 + cc]));
    float b = lrelu_f(fmaf(bfhi(u), stats[cc + 1], stats[129 + cc]));
    z[i] = pack2(a, b);
}

// ---------- residual add (bf16 + bf16 -> bf16) ----------
__global__ __launch_bounds__(256) void combine_kernel(const uint32_t* __restrict__ a,
                                                      const uint32_t* __restrict__ b,
                                                      uint32_t* __restrict__ t, int total2) {
    int i = blockIdx.x * 256 + threadIdx.x;
    if (i >= total2) return;
    uint32_t ua = a[i], ub = b[i];
    t[i] = pack2(bflo(ua) + bflo(ub), bfhi(ua) + bfhi(ub));
}

// ---------- final fc2 dot (K=64, z2 fp32, params fp32) -> fp32 out ----------
__global__ __launch_bounds__(256) void final_fc2(const float* __restrict__ z2,
                                                 const float* __restrict__ w2,
                                                 const float* __restrict__ b2,
                                                 float* __restrict__ out, int M) {
    int gid = blockIdx.x * 256 + threadIdx.x;
    int v = gid >> 6, lane = gid & 63;
    if (v >= M) return;
    float val = z2[(size_t)v * 64 + lane] * w2[lane];
#pragma unroll
    for (int off = 32; off > 0; off >>= 1) val += __shfl_down(val, off, 64);
    if (lane == 0) out[v] = val + b2[0];          // fp32 store (ref output dtype)
}

// ---------- launch ----------
extern "C" void kernel_launch(void* const* d_in, const int* in_sizes, int n_in,
                              void* d_out, int out_size, void* d_ws, size_t ws_size,
                              hipStream_t stream) {
    const void* x = d_in[0];                               // [M][128] bf16 or fp32
    const int* ei = (const int*)d_in[1];                   // int32 or int64 [2][E]
    const int M = in_sizes[0] / HID;                       // 100000
    const int E = in_sizes[1] / 2;                         // 1600000

    // workspace layout — total ~84.3 MB
    const size_t FEAT = (size_t)M * HID * 2;               // 25.6 MB per bf16 buffer
    char* p = (char*)d_ws;
    uint16_t* H0 = (uint16_t*)p; p += FEAT;                // residual, persists
    uint16_t* P  = (uint16_t*)p; p += FEAT;
    uint16_t* Q  = (uint16_t*)p; p += FEAT;                // x-conv, then rotations, then fp32 Z2
    uint16_t* WT = (uint16_t*)p; p += 8 * 16384 * 2;       // 8 transposed weight slots
    float* params = (float*)p; p += 8192;                  // canonical fp32 param vectors
    int* rowptr  = (int*)p; p += ((size_t)M + 32) * 4;
    int* cursor  = (int*)p; p += ((size_t)M + 32) * 4;
    int* csr     = (int*)p; p += (size_t)E * 4;
    int* scanbuf = (int*)p; p += 4096;
    float* stats = (float*)p; p += 1024;
    int* flagE   = (int*)p; p += 128;
    int* flagF   = (int*)p; p += 128;

    const size_t needed = (size_t)(p - (char*)d_ws);
    if (needed > ws_size) {                                // diagnostic sentinel
        sentinel_kernel<<<(out_size + 255) / 256, 256, 0, stream>>>(
            (float*)d_out, out_size);
        return;
    }

    uint16_t* wt[8];
    for (int i = 0; i < 8; ++i) wt[i] = WT + (size_t)i * 16384;

    // 0) dtype probes
    detect_e_kernel<<<1, 64, 0, stream>>>(ei, flagE);
    detect_f_kernel<<<1, 64, 0, stream>>>((const uint32_t*)x, flagF);

    // 1) canonicalize params
    TransArgs ta;
    const int widx[8] = {2, 4, 6, 7, 9, 10, 12, 19};       // W_in, Wl1, Wr1, Wl2, Wr2, Wl3, Wr3, Wfc1
    for (int i = 0; i < 8; ++i) {
        ta.src[i] = d_in[widx[i]];
        ta.dst[i] = wt[i];
        ta.nrows[i] = (i == 7) ? 64 : 128;
    }
    transpose_w<<<512, 256, 0, stream>>>(ta, flagF);

    ParamArgs pa;
    const int pidx[14] = {3, 5, 8, 11, 13, 15, 17, 14, 16, 18, 20, 21, 22, 22};
    const int poff[14] = {0, 128, 256, 384, 512, 640, 768, 896, 1024, 1152, 1280, 1344, 1408, 1409};
    const int pcnt[14] = {128, 128, 128, 128, 128, 128, 128, 128, 128, 128, 64, 64, 1, 0};
    for (int i = 0; i < 14; ++i) { pa.src[i] = d_in[pidx[i]]; pa.off[i] = poff[i]; pa.cnt[i] = pcnt[i]; }
    convert_params<<<14, 128, 0, stream>>>(pa, params, flagF);
    // params map: 0 b_in | 128/256/384 b_l1..3 | 512/640/768 g1..3 | 896/1024/1152 be1..3
    //             1280 b_fc1[64] | 1344 W_fc2[64] | 1408 b_fc2[1]

    const int total2 = M * (HID / 2);                      // uint32 elements per feature buf
    const int ew_grid = (total2 + 255) / 256;
    convert_x<<<ew_grid, 256, 0, stream>>>(x, (uint32_t*)Q, flagF, total2);

    // 2) CSR build (cursor holds deg, then fill cursors)
    hipMemsetAsync(cursor, 0, (size_t)(M + 1) * sizeof(int), stream);
    const int egrid = (E + 255) / 256;
    hist_kernel<<<egrid, 256, 0, stream>>>(ei, flagE, cursor, E);
    const int CH = (M + 1023) >> 10;
    scan_a<<<4, 256, 0, stream>>>(cursor, scanbuf, M, CH);
    scan_b<<<1, 1024, 0, stream>>>(scanbuf);
    scan_c<<<4, 256, 0, stream>>>(cursor, scanbuf, rowptr, M, E, CH);
    fill_kernel<<<egrid, 256, 0, stream>>>(ei, flagE, cursor, csr, E);

    const int gemm_grid = (M + 127) / 128;
    const int node_grid = (M + 3) / 4;
    const int rpb = (M + 255) / 256;

    // 3) h0 = x @ W_in^T + b_in  (residual, bf16; reads converted x in Q)
    gemm_kernel<128, 1, false, false><<<gemm_grid, 256, 0, stream>>>(
        Q, wt[0], nullptr, nullptr, params + 0, H0, M);

    // 4) three SAGE layers (gather cur -> z; gemm in-place over z)
    uint16_t* wtl[3] = {wt[1], wt[3], wt[5]};
    uint16_t* wtr[3] = {wt[2], wt[4], wt[6]};
    uint16_t* cur = H0;
    uint16_t* dstb[3] = {P, Q, P};
    for (int l = 0; l < 3; ++l) {
        uint16_t* z = dstb[l];
        gather_kernel<<<node_grid, 256, 0, stream>>>(
            (const uint32_t*)cur, rowptr, csr, (uint32_t*)z, M);
        gemm_kernel<128, 2, false, false><<<gemm_grid, 256, 0, stream>>>(
            z, wtl[l], cur, wtr[l], params + 128 + l * 128, z, M);
        hipMemsetAsync(stats, 0, 1024, stream);
        bn_stats<<<256, 256, 0, stream>>>((const uint32_t*)z, stats, M, rpb);
        bn_finalize<<<1, 128, 0, stream>>>(stats, params + 512 + l * 128,
                                           params + 896 + l * 128, M);
        bn_apply<<<ew_grid, 256, 0, stream>>>((uint32_t*)z, stats, total2);
        cur = z;
    }

    // 5) residual add (in-place into P), fc1 (+lrelu, fp32 out into Q), fc2
    combine_kernel<<<ew_grid, 256, 0, stream>>>(
        (const uint32_t*)cur, (const uint32_t*)H0, (uint32_t*)P, total2);
    float* Z2 = (float*)Q;                                  // [M][64] fp32 (25.6 MB slot)
    gemm_kernel<64, 1, true, true><<<gemm_grid, 256, 0, stream>>>(
        P, wt[7], nullptr, nullptr, params + 1280, Z2, M);
    final_fc2<<<node_grid, 256, 0, stream>>>(
        Z2, params + 1344, params + 1408, (float*)d_out, M);
}

// Round 5
// 884.020 us; speedup vs baseline: 1.6190x; 1.6190x over previous
//
#include <hip/hip_runtime.h>
#include <cstdint>
#include <cstddef>

#define HID 128

typedef __bf16 bf16x8 __attribute__((ext_vector_type(8)));
typedef float f32x4 __attribute__((ext_vector_type(4)));

// ---------- helpers ----------
__device__ __forceinline__ float bf2f(uint32_t u) {
    union { uint32_t i; float f; } x; x.i = u << 16; return x.f;
}
__device__ __forceinline__ float bflo(uint32_t p) { return bf2f(p & 0xffffu); }
__device__ __forceinline__ float bfhi(uint32_t p) { return bf2f(p >> 16); }
__device__ __forceinline__ float bfs(const uint16_t* p) { return bf2f((uint32_t)*p); }
__device__ __forceinline__ uint16_t f2bf(float f) {
    union { float f; uint32_t i; } x; x.f = f;
    uint32_t u = x.i;
    return (uint16_t)((u + 0x7fffu + ((u >> 16) & 1u)) >> 16);   // RNE
}
__device__ __forceinline__ uint32_t pack2(float a, float b) {
    return (uint32_t)f2bf(a) | ((uint32_t)f2bf(b) << 16);
}
__device__ __forceinline__ float lrelu_f(float v) { return v > 0.f ? v : 0.01f * v; }
__device__ __forceinline__ bf16x8 ldfrag(const uint16_t* p) {
    union { uint4 u; bf16x8 b; } c;
    c.u = *(const uint4*)p;
    return c.b;
}

// ---------- ws-too-small sentinel ----------
__global__ __launch_bounds__(256) void sentinel_kernel(float* out, int n) {
    int i = blockIdx.x * 256 + threadIdx.x;
    if (i < n) out[i] = 65536.0f;
}

// ---------- dtype probes ----------
__global__ void detect_e_kernel(const int* __restrict__ ei, int* __restrict__ flagE) {
    int lane = threadIdx.x;                       // 64 threads
    int w = ei[2 * lane + 1];
    unsigned long long b = __ballot(w != 0);
    if (lane == 0) flagE[0] = (b == 0ULL) ? 1 : 0;   // 1 = int64
}
__global__ void detect_f_kernel(const uint32_t* __restrict__ x, int* __restrict__ flagF) {
    int lane = threadIdx.x;                       // 64 threads
    uint32_t e = (x[lane] >> 7) & 0xFFu;
    unsigned long long b = __ballot(e >= 64u && e <= 144u);
    if (lane == 0) flagF[0] = (b == ~0ULL) ? 0 : 1;  // 1 = fp32, 0 = bf16
}

// ---------- weight canonicalize: W[n][k] -> bf16 copy (same layout) ----------
struct WArgs {
    const void* src[8];
    uint16_t* dst[8];
    int nrows[8];
};
__global__ __launch_bounds__(256) void convert_w(WArgs a, const int* __restrict__ flagF) {
    int mat = blockIdx.x >> 6;                    // 64 blocks per matrix
    int idx = ((blockIdx.x & 63) << 8) + threadIdx.x;
    if (idx < a.nrows[mat] * HID) {
        a.dst[mat][idx] = flagF[0] ? f2bf(((const float*)a.src[mat])[idx])
                                   : ((const uint16_t*)a.src[mat])[idx];
    }
}

// ---------- param vectors -> canonical fp32 buffer ----------
struct ParamArgs {
    const void* src[14];
    int off[14];
    int cnt[14];
};
__global__ __launch_bounds__(128) void convert_params(ParamArgs pa, float* __restrict__ params,
                                                      const int* __restrict__ flagF) {
    int b = blockIdx.x, t = threadIdx.x;          // 14 blocks x 128
    if (t < pa.cnt[b]) {
        float v = flagF[0] ? ((const float*)pa.src[b])[t]
                           : bfs(&((const uint16_t*)pa.src[b])[t]);
        params[pa.off[b] + t] = v;
    }
}

// ---------- x -> canonical bf16 feature buffer ----------
__global__ __launch_bounds__(256) void convert_x(const void* __restrict__ x,
                                                 uint32_t* __restrict__ dst,
                                                 const int* __restrict__ flagF, int total2) {
    int i = blockIdx.x * 256 + threadIdx.x;
    if (i >= total2) return;
    if (flagF[0]) {
        float2 v = ((const float2*)x)[i];
        dst[i] = pack2(v.x, v.y);
    } else {
        dst[i] = ((const uint32_t*)x)[i];
    }
}

// ---------- CSR build ----------
__global__ __launch_bounds__(256) void hist_kernel(const int* __restrict__ ei,
                                                   const int* __restrict__ flagE,
                                                   int* deg, int E) {
    int e = blockIdx.x * 256 + threadIdx.x;
    if (e < E) {
        int d = flagE[0] ? ei[2 * (E + e)] : ei[E + e];
        atomicAdd(&deg[d], 1);
    }
}
__global__ __launch_bounds__(256) void scan_a(const int* deg, int* scanbuf, int M, int CH) {
    int i = blockIdx.x * 256 + threadIdx.x;       // 0..1023
    int s = i * CH, e = min(s + CH, M);
    int t = 0;
    for (int j = s; j < e; ++j) t += deg[j];
    scanbuf[i] = t;
}
__global__ __launch_bounds__(1024) void scan_b(int* scanbuf) {
    __shared__ int sm[1024];
    int tid = threadIdx.x;
    int v = scanbuf[tid];
    sm[tid] = v;
    __syncthreads();
    for (int off = 1; off < 1024; off <<= 1) {
        int t = (tid >= off) ? sm[tid - off] : 0;
        __syncthreads();
        sm[tid] += t;
        __syncthreads();
    }
    scanbuf[tid] = sm[tid] - v;                   // exclusive prefix
}
__global__ __launch_bounds__(256) void scan_c(int* deg_then_cursor, const int* scanbuf,
                                              int* rowptr, int M, int E, int CH) {
    int i = blockIdx.x * 256 + threadIdx.x;       // 0..1023
    int run = scanbuf[i];
    int s = i * CH, e = min(s + CH, M);
    for (int j = s; j < e; ++j) {
        int d = deg_then_cursor[j];
        rowptr[j] = run;
        deg_then_cursor[j] = run;                 // becomes fill cursor
        run += d;
    }
    if (i == 0) rowptr[M] = E;
}
__global__ __launch_bounds__(256) void fill_kernel(const int* __restrict__ ei,
                                                   const int* __restrict__ flagE,
                                                   int* cursor, int* csr, int E) {
    int e = blockIdx.x * 256 + threadIdx.x;
    if (e < E) {
        int isl = flagE[0];
        int s = isl ? ei[2 * e] : ei[e];
        int d = isl ? ei[2 * (E + e)] : ei[E + e];
        int p = atomicAdd(&cursor[d], 1);
        csr[p] = s;
    }
}

// ---------- max aggregation: 4 nodes/wave (16 lanes x uint4), 2-edge unroll ----------
__global__ __launch_bounds__(256) void gather_kernel(const uint4* __restrict__ cur,
                                                     const int* __restrict__ rowptr,
                                                     const int* __restrict__ csr,
                                                     uint4* __restrict__ agg, int M) {
    int gid = blockIdx.x * 256 + threadIdx.x;
    int node = gid >> 4;
    int sl = threadIdx.x & 15;                    // 16-lane subgroup, 16 B each
    if (node >= M) return;
    int b = rowptr[node], e = rowptr[node + 1];
    float m[8];
#pragma unroll
    for (int j = 0; j < 8; ++j) m[j] = -INFINITY;
    int i = b;
    for (; i + 2 <= e; i += 2) {
        int s0 = csr[i], s1 = csr[i + 1];
        uint4 u0 = cur[(size_t)s0 * 16 + sl];
        uint4 u1 = cur[(size_t)s1 * 16 + sl];
        uint32_t w0[4] = {u0.x, u0.y, u0.z, u0.w};
        uint32_t w1[4] = {u1.x, u1.y, u1.z, u1.w};
#pragma unroll
        for (int j = 0; j < 4; ++j) {
            m[2 * j]     = fmaxf(m[2 * j],     fmaxf(bflo(w0[j]), bflo(w1[j])));
            m[2 * j + 1] = fmaxf(m[2 * j + 1], fmaxf(bfhi(w0[j]), bfhi(w1[j])));
        }
    }
    if (i < e) {
        int s0 = csr[i];
        uint4 u0 = cur[(size_t)s0 * 16 + sl];
        uint32_t w0[4] = {u0.x, u0.y, u0.z, u0.w};
#pragma unroll
        for (int j = 0; j < 4; ++j) {
            m[2 * j]     = fmaxf(m[2 * j],     bflo(w0[j]));
            m[2 * j + 1] = fmaxf(m[2 * j + 1], bfhi(w0[j]));
        }
    }
    if (b == e) {
#pragma unroll
        for (int j = 0; j < 8; ++j) m[j] = 0.f;   // no neighbors -> 0 (isfinite rule)
    }
    uint4 o;
    o.x = pack2(m[0], m[1]); o.y = pack2(m[2], m[3]);
    o.z = pack2(m[4], m[5]); o.w = pack2(m[6], m[7]);
    agg[(size_t)node * 16 + sl] = o;
}

// ---------- MFMA GEMM: out[M][N] = sum_s A_s @ W_s^T + bias ----------
// Computes D = W · X^T with v_mfma_f32_16x16x32_bf16:
//   A-operand = W[n][k] (native layout), B-operand = X^T (B[k][m] = X[m][k]).
//   D frag: node m = lane&15, feature n = (lane>>4)*4 + r  -> ushort4/float4 stores.
// In-place (out aliases A0) safe: all global reads precede the final barrier;
// stores after; blocks touch only their own 128 rows.
template<int N, int NSRC, bool ACT, bool OUTF32>
__global__ __launch_bounds__(256) void gemm_mfma(
    const uint16_t* __restrict__ A0, const uint16_t* __restrict__ W0,
    const uint16_t* __restrict__ A1, const uint16_t* __restrict__ W1,
    const float* __restrict__ bias, void* __restrict__ out_, int M)
{
    constexpr int LDT = 40;                       // row stride in uint16 (80 B, pad 16 B)
    constexpr int WAVES_N = N / 64;               // 2 (N=128) or 1 (N=64)
    constexpr int WAVES_M = 4 / WAVES_N;          // 2 or 4
    constexpr int MT = 8 / WAVES_M;               // m-tiles/wave: 4 or 2
    constexpr int NT = 4;                         // n-tiles/wave (64 cols)
    __shared__ uint16_t LX[128 * LDT];            // X tile [row][k32]
    __shared__ uint16_t LW[N * LDT];              // W tile [n][k32]
    const int tid = threadIdx.x;
    const int wave = tid >> 6, lane = tid & 63;
    const int l15 = lane & 15, lkg = lane >> 4;   // k-group 0..3
    const int wn = (wave % WAVES_N) * 64;
    const int wm = (wave / WAVES_N) * (128 / WAVES_M);
    const int row0 = blockIdx.x * 128;

    f32x4 acc[NT][MT];
#pragma unroll
    for (int nt = 0; nt < NT; ++nt)
#pragma unroll
        for (int mt = 0; mt < MT; ++mt) {
            f32x4 z4 = {0.f, 0.f, 0.f, 0.f};
            acc[nt][mt] = z4;
        }

#pragma unroll 1
    for (int s = 0; s < NSRC; ++s) {
        const uint16_t* Ag = (s == 0) ? A0 : A1;
        const uint16_t* Wg = (s == 0) ? W0 : W1;
#pragma unroll 1
        for (int kc = 0; kc < 4; ++kc) {
            __syncthreads();
            // stage X chunk: 128 rows x 32 k (64 B/row), 512 uint4
            {
                int id = tid;
#pragma unroll
                for (int it = 0; it < 2; ++it, id += 256) {
                    int r = id >> 2, ko = (id & 3) * 8;
                    uint4 v = make_uint4(0, 0, 0, 0);
                    int gr = row0 + r;
                    if (gr < M) v = *(const uint4*)(Ag + (size_t)gr * HID + kc * 32 + ko);
                    *(uint4*)&LX[r * LDT + ko] = v;
                }
            }
            // stage W chunk: N rows x 32 k
            {
                int id = tid;
#pragma unroll
                for (int it = 0; it < N / 64; ++it, id += 256) {
                    int r = id >> 2, ko = (id & 3) * 8;
                    *(uint4*)&LW[r * LDT + ko] = *(const uint4*)(Wg + (size_t)r * HID + kc * 32 + ko);
                }
            }
            __syncthreads();
            bf16x8 xf[MT], wf[NT];
#pragma unroll
            for (int mt = 0; mt < MT; ++mt)
                xf[mt] = ldfrag(&LX[(wm + mt * 16 + l15) * LDT + lkg * 8]);
#pragma unroll
            for (int nt = 0; nt < NT; ++nt)
                wf[nt] = ldfrag(&LW[(wn + nt * 16 + l15) * LDT + lkg * 8]);
#pragma unroll
            for (int nt = 0; nt < NT; ++nt)
#pragma unroll
                for (int mt = 0; mt < MT; ++mt)
                    acc[nt][mt] = __builtin_amdgcn_mfma_f32_16x16x32_bf16(
                        wf[nt], xf[mt], acc[nt][mt], 0, 0, 0);
        }
    }

#pragma unroll
    for (int nt = 0; nt < NT; ++nt) {
        int n0 = wn + nt * 16 + lkg * 4;
        float b0 = bias[n0], b1 = bias[n0 + 1], b2 = bias[n0 + 2], b3 = bias[n0 + 3];
#pragma unroll
        for (int mt = 0; mt < MT; ++mt) {
            int m = row0 + wm + mt * 16 + l15;
            if (m < M) {
                f32x4 f = acc[nt][mt];
                float o0 = f[0] + b0, o1 = f[1] + b1, o2 = f[2] + b2, o3 = f[3] + b3;
                if constexpr (ACT) {
                    o0 = lrelu_f(o0); o1 = lrelu_f(o1); o2 = lrelu_f(o2); o3 = lrelu_f(o3);
                }
                if constexpr (OUTF32) {
                    *(float4*)((float*)out_ + (size_t)m * N + n0) = make_float4(o0, o1, o2, o3);
                } else {
                    ushort4 ov;
                    ov.x = f2bf(o0); ov.y = f2bf(o1); ov.z = f2bf(o2); ov.w = f2bf(o3);
                    *(ushort4*)((uint16_t*)out_ + (size_t)m * N + n0) = ov;
                }
            }
        }
    }
}

// ---------- batch norm over bf16 z ----------
__global__ __launch_bounds__(256) void bn_stats(const uint32_t* __restrict__ z,
                                                float* __restrict__ stats, int M, int rpb) {
    __shared__ float4 red[256];
    int c2 = threadIdx.x & 63;                    // uint32 column (2 features)
    int part = threadIdx.x >> 6;                  // 0..3
    int s0 = blockIdx.x * rpb, e0 = min(s0 + rpb, M);
    float sl = 0.f, s2l = 0.f, sh = 0.f, s2h = 0.f;
    for (int r = s0 + part; r < e0; r += 4) {
        uint32_t u = z[(size_t)r * 64 + c2];
        float a = bflo(u), b = bfhi(u);
        sl += a; s2l = fmaf(a, a, s2l);
        sh += b; s2h = fmaf(b, b, s2h);
    }
    red[threadIdx.x] = make_float4(sl, s2l, sh, s2h);
    __syncthreads();
    if (threadIdx.x < 64) {
        float4 v = red[threadIdx.x];
        float4 v1 = red[threadIdx.x + 64], v2 = red[threadIdx.x + 128], v3 = red[threadIdx.x + 192];
        v.x += v1.x + v2.x + v3.x; v.y += v1.y + v2.y + v3.y;
        v.z += v1.z + v2.z + v3.z; v.w += v1.w + v2.w + v3.w;
        int cc = c2 * 2;
        atomicAdd(&stats[cc], v.x);
        atomicAdd(&stats[128 + cc], v.y);
        atomicAdd(&stats[cc + 1], v.z);
        atomicAdd(&stats[129 + cc], v.w);
    }
}
__global__ void bn_finalize(float* stats, const float* __restrict__ g,
                            const float* __restrict__ be, int M) {
    int c = threadIdx.x;                          // 128 threads
    float mean = stats[c] / (float)M;
    float var = stats[128 + c] / (float)M - mean * mean;
    float sc = g[c] * rsqrtf(var + 1e-5f);
    stats[c] = sc;
    stats[128 + c] = be[c] - mean * sc;
}
__global__ __launch_bounds__(256) void bn_apply(uint32_t* __restrict__ z,
                                                const float* __restrict__ stats, int total2) {
    int i = blockIdx.x * 256 + threadIdx.x;
    if (i >= total2) return;
    int cc = (i & 63) * 2;
    uint32_t u = z[i];
    float a = lrelu_f(fmaf(bflo(u), stats[cc], stats[128 + cc]));
    float b = lrelu_f(fmaf(bfhi(u), stats[cc + 1], stats[129 + cc]));
    z[i] = pack2(a, b);
}

// ---------- residual add (bf16 + bf16 -> bf16) ----------
__global__ __launch_bounds__(256) void combine_kernel(const uint32_t* __restrict__ a,
                                                      const uint32_t* __restrict__ b,
                                                      uint32_t* __restrict__ t, int total2) {
    int i = blockIdx.x * 256 + threadIdx.x;
    if (i >= total2) return;
    uint32_t ua = a[i], ub = b[i];
    t[i] = pack2(bflo(ua) + bflo(ub), bfhi(ua) + bfhi(ub));
}

// ---------- final fc2 dot (K=64, z2 fp32, params fp32) -> fp32 out ----------
__global__ __launch_bounds__(256) void final_fc2(const float* __restrict__ z2,
                                                 const float* __restrict__ w2,
                                                 const float* __restrict__ b2,
                                                 float* __restrict__ out, int M) {
    int gid = blockIdx.x * 256 + threadIdx.x;
    int v = gid >> 6, lane = gid & 63;
    if (v >= M) return;
    float val = z2[(size_t)v * 64 + lane] * w2[lane];
#pragma unroll
    for (int off = 32; off > 0; off >>= 1) val += __shfl_down(val, off, 64);
    if (lane == 0) out[v] = val + b2[0];          // fp32 store (ref output dtype)
}

// ---------- launch ----------
extern "C" void kernel_launch(void* const* d_in, const int* in_sizes, int n_in,
                              void* d_out, int out_size, void* d_ws, size_t ws_size,
                              hipStream_t stream) {
    const void* x = d_in[0];                               // [M][128] bf16 or fp32
    const int* ei = (const int*)d_in[1];                   // int32 or int64 [2][E]
    const int M = in_sizes[0] / HID;                       // 100000
    const int E = in_sizes[1] / 2;                         // 1600000

    // workspace layout — total ~84.3 MB
    const size_t FEAT = (size_t)M * HID * 2;               // 25.6 MB per bf16 buffer
    char* p = (char*)d_ws;
    uint16_t* H0 = (uint16_t*)p; p += FEAT;                // residual, persists
    uint16_t* P  = (uint16_t*)p; p += FEAT;
    uint16_t* Q  = (uint16_t*)p; p += FEAT;                // x-conv, rotations, fp32 Z2
    uint16_t* WT = (uint16_t*)p; p += 8 * 16384 * 2;       // 8 bf16 weight slots [n][k]
    float* params = (float*)p; p += 8192;                  // canonical fp32 param vectors
    int* rowptr  = (int*)p; p += ((size_t)M + 32) * 4;
    int* cursor  = (int*)p; p += ((size_t)M + 32) * 4;
    int* csr     = (int*)p; p += (size_t)E * 4;
    int* scanbuf = (int*)p; p += 4096;
    float* stats = (float*)p; p += 1024;
    int* flagE   = (int*)p; p += 128;
    int* flagF   = (int*)p; p += 128;

    const size_t needed = (size_t)(p - (char*)d_ws);
    if (needed > ws_size) {                                // diagnostic sentinel
        sentinel_kernel<<<(out_size + 255) / 256, 256, 0, stream>>>(
            (float*)d_out, out_size);
        return;
    }

    uint16_t* wt[8];
    for (int i = 0; i < 8; ++i) wt[i] = WT + (size_t)i * 16384;

    // 0) dtype probes
    detect_e_kernel<<<1, 64, 0, stream>>>(ei, flagE);
    detect_f_kernel<<<1, 64, 0, stream>>>((const uint32_t*)x, flagF);

    // 1) canonicalize weights (bf16 copy, native [n][k] layout) + params (fp32)
    WArgs wa;
    const int widx[8] = {2, 4, 6, 7, 9, 10, 12, 19};       // W_in, Wl1, Wr1, Wl2, Wr2, Wl3, Wr3, Wfc1
    for (int i = 0; i < 8; ++i) {
        wa.src[i] = d_in[widx[i]];
        wa.dst[i] = wt[i];
        wa.nrows[i] = (i == 7) ? 64 : 128;
    }
    convert_w<<<512, 256, 0, stream>>>(wa, flagF);

    ParamArgs pa;
    const int pidx[14] = {3, 5, 8, 11, 13, 15, 17, 14, 16, 18, 20, 21, 22, 22};
    const int poff[14] = {0, 128, 256, 384, 512, 640, 768, 896, 1024, 1152, 1280, 1344, 1408, 1409};
    const int pcnt[14] = {128, 128, 128, 128, 128, 128, 128, 128, 128, 128, 64, 64, 1, 0};
    for (int i = 0; i < 14; ++i) { pa.src[i] = d_in[pidx[i]]; pa.off[i] = poff[i]; pa.cnt[i] = pcnt[i]; }
    convert_params<<<14, 128, 0, stream>>>(pa, params, flagF);
    // params map: 0 b_in | 128/256/384 b_l1..3 | 512/640/768 g1..3 | 896/1024/1152 be1..3
    //             1280 b_fc1[64] | 1344 W_fc2[64] | 1408 b_fc2[1]

    const int total2 = M * (HID / 2);                      // uint32 elems per feature buf
    const int ew_grid = (total2 + 255) / 256;
    convert_x<<<ew_grid, 256, 0, stream>>>(x, (uint32_t*)Q, flagF, total2);

    // 2) CSR build (cursor holds deg, then fill cursors)
    hipMemsetAsync(cursor, 0, (size_t)(M + 1) * sizeof(int), stream);
    const int egrid = (E + 255) / 256;
    hist_kernel<<<egrid, 256, 0, stream>>>(ei, flagE, cursor, E);
    const int CH = (M + 1023) >> 10;
    scan_a<<<4, 256, 0, stream>>>(cursor, scanbuf, M, CH);
    scan_b<<<1, 1024, 0, stream>>>(scanbuf);
    scan_c<<<4, 256, 0, stream>>>(cursor, scanbuf, rowptr, M, E, CH);
    fill_kernel<<<egrid, 256, 0, stream>>>(ei, flagE, cursor, csr, E);

    const int gemm_grid = (M + 127) / 128;
    const int gather_grid = (M + 15) / 16;                 // 4 nodes per wave
    const int fc2_grid = (M + 3) / 4;                      // 1 node per wave
    const int rpb = (M + 255) / 256;

    // 3) h0 = x @ W_in^T + b_in  (residual, bf16)
    gemm_mfma<128, 1, false, false><<<gemm_grid, 256, 0, stream>>>(
        Q, wt[0], nullptr, nullptr, params + 0, H0, M);

    // 4) three SAGE layers (gather cur -> z; gemm in-place over z)
    uint16_t* wtl[3] = {wt[1], wt[3], wt[5]};
    uint16_t* wtr[3] = {wt[2], wt[4], wt[6]};
    uint16_t* cur = H0;
    uint16_t* dstb[3] = {P, Q, P};
    for (int l = 0; l < 3; ++l) {
        uint16_t* z = dstb[l];
        gather_kernel<<<gather_grid, 256, 0, stream>>>(
            (const uint4*)cur, rowptr, csr, (uint4*)z, M);
        gemm_mfma<128, 2, false, false><<<gemm_grid, 256, 0, stream>>>(
            z, wtl[l], cur, wtr[l], params + 128 + l * 128, z, M);
        hipMemsetAsync(stats, 0, 1024, stream);
        bn_stats<<<256, 256, 0, stream>>>((const uint32_t*)z, stats, M, rpb);
        bn_finalize<<<1, 128, 0, stream>>>(stats, params + 512 + l * 128,
                                           params + 896 + l * 128, M);
        bn_apply<<<ew_grid, 256, 0, stream>>>((uint32_t*)z, stats, total2);
        cur = z;
    }

    // 5) residual add (into P), fc1 (+lrelu, fp32 out into Q), fc2
    combine_kernel<<<ew_grid, 256, 0, stream>>>(
        (const uint32_t*)cur, (const uint32_t*)H0, (uint32_t*)P, total2);
    float* Z2 = (float*)Q;                                  // [M][64] fp32 (25.6 MB slot)
    gemm_mfma<64, 1, true, true><<<gemm_grid, 256, 0, stream>>>(
        P, wt[7], nullptr, nullptr, params + 1280, Z2, M);
    final_fc2<<<fc2_grid, 256, 0, stream>>>(
        Z2, params + 1344, params + 1408, (float*)d_out, M);
}